// Round 1
// baseline (2748.169 us; speedup 1.0000x reference)
//
#include <hip/hip_runtime.h>
#include <math.h>

#define C_ 8
#define K_ 64
#define D_ 32
#define N_ 2048

// ws layout (floats):
//   eas   [C][K][D]  @ 0        (exp(-an_s))
//   els   [C][D]     @ 16384    (exp(-log_scale))
//   CONST [C]        @ 16640    (-sum(an_s) - 0.5*D*log(2pi) - sum(log_scale))
//   logp  [C][N]     @ 16648
//   Bn    [C][N]     @ 33032
//   A     [C][N]     @ 49416

__global__ __launch_bounds__(256) void k_pre(const float* __restrict__ an_s,
                                             const float* __restrict__ log_scale,
                                             float* __restrict__ ws) {
  int g = blockIdx.x * 256 + threadIdx.x;
  if (g < C_ * K_ * D_) ws[g] = expf(-an_s[g]);
  if (g < C_ * D_) ws[16384 + g] = expf(-log_scale[g]);
}

__global__ __launch_bounds__(512) void k_const(const float* __restrict__ an_s,
                                               const float* __restrict__ log_scale,
                                               float* __restrict__ ws) {
  int tid = threadIdx.x;
  int c = tid >> 6, lane = tid & 63;
  float acc = 0.f;
  for (int r = 0; r < 32; ++r) acc += an_s[c * 2048 + r * 64 + lane];
  if (lane < 32) acc += log_scale[c * 32 + lane];
  for (int off = 32; off; off >>= 1) acc += __shfl_down(acc, off);
  if (lane == 0) ws[16640 + c] = -acc - 29.406033062549525f;  // 0.5*32*log(2pi)
}

// One layer of the inverse flow. PIN = parity of the masked (input) components.
// x[i] <-> z[2i+PIN] (kept), y[i] <-> z[2i+1-PIN] (updated).
// Each of the 4 waves computes hidden units [16w,16w+16); partial GEMM2 sums are
// exchanged via XOR-swizzled LDS; z is replicated per wave (bitwise identical).
template <int PIN>
__device__ __forceinline__ void layer_step(
    int c, int k, int w, int idx0, float (&x)[16], float (&y)[16], float& ld,
    float* lds,
    const float* __restrict__ sW1, const float* __restrict__ sb1,
    const float* __restrict__ sW2, const float* __restrict__ sb2,
    const float* __restrict__ tW1, const float* __restrict__ tb1,
    const float* __restrict__ tW2, const float* __restrict__ tb2,
    const float* __restrict__ an_t, const float* __restrict__ eas) {
  const int ck = c * K_ + k;
  const float* W1s = sW1 + ck * (2 * D_ * D_);
  const float* b1s = sb1 + ck * (2 * D_);
  const float* W2s = sW2 + ck * (D_ * 2 * D_);
  const float* b2s = sb2 + ck * D_;
  const float* W1t = tW1 + ck * (2 * D_ * D_);
  const float* b1t = tb1 + ck * (2 * D_);
  const float* W2t = tW2 + ck * (D_ * 2 * D_);
  const float* b2t = tb2 + ck * D_;
  const float* at = an_t + ck * D_;
  const float* ea = eas + ck * D_;

  // ActNorm inverse on full z (an_s sum folded into CONST)
#pragma unroll
  for (int i = 0; i < 16; ++i) {
    x[i] = (x[i] - at[2 * i + PIN]) * ea[2 * i + PIN];
    y[i] = (y[i] - at[2 * i + (1 - PIN)]) * ea[2 * i + (1 - PIN)];
  }

  float h[16], p[16];
  const int jb = w * 16;
  const int buf = (k & 1) * 2;  // LDS double-buffer select
  const int basew = idx0 ^ (w * 16);

  // ---- s MLP: GEMM1 (16 inputs -> this wave's 16 hidden) ----
#pragma unroll
  for (int jj = 0; jj < 16; ++jj) {
    float acc = b1s[jb + jj];
#pragma unroll
    for (int i = 0; i < 16; ++i) acc += W1s[(jb + jj) * D_ + 2 * i + PIN] * x[i];
    h[jj] = fmaxf(acc, 0.f);
  }
  // GEMM2 partial: 16 needed outputs over this wave's 16 hidden
#pragma unroll
  for (int o = 0; o < 16; ++o) {
    const int dout = 2 * o + (1 - PIN);
    float acc = (w == 0) ? b2s[dout] : 0.f;
#pragma unroll
    for (int jj = 0; jj < 16; ++jj) acc += W2s[dout * 2 * D_ + jb + jj] * h[jj];
    p[o] = acc;
  }
  {
    float* B = lds + buf * 4096;
#pragma unroll
    for (int q = 0; q < 4; ++q)
      *(float4*)(B + (basew ^ (q * 4))) =
          make_float4(p[4 * q], p[4 * q + 1], p[4 * q + 2], p[4 * q + 3]);
  }

  // ---- t MLP ----
#pragma unroll
  for (int jj = 0; jj < 16; ++jj) {
    float acc = b1t[jb + jj];
#pragma unroll
    for (int i = 0; i < 16; ++i) acc += W1t[(jb + jj) * D_ + 2 * i + PIN] * x[i];
    h[jj] = fmaxf(acc, 0.f);
  }
#pragma unroll
  for (int o = 0; o < 16; ++o) {
    const int dout = 2 * o + (1 - PIN);
    float acc = (w == 0) ? b2t[dout] : 0.f;
#pragma unroll
    for (int jj = 0; jj < 16; ++jj) acc += W2t[dout * 2 * D_ + jb + jj] * h[jj];
    p[o] = acc;
  }
  {
    float* B = lds + (buf + 1) * 4096;
#pragma unroll
    for (int q = 0; q < 4; ++q)
      *(float4*)(B + (basew ^ (q * 4))) =
          make_float4(p[4 * q], p[4 * q + 1], p[4 * q + 2], p[4 * q + 3]);
  }

  __syncthreads();

  // reduce s partials across the 4 waves (same order in every wave -> bitwise identical)
  float sv[16];
  {
    float* B = lds + buf * 4096;
#pragma unroll
    for (int g = 0; g < 16; ++g) {
      float4 v = *(const float4*)(B + (idx0 ^ (g * 4)));
      const int ob = (g & 3) * 4;
      if (g < 4) { sv[ob] = v.x; sv[ob + 1] = v.y; sv[ob + 2] = v.z; sv[ob + 3] = v.w; }
      else       { sv[ob] += v.x; sv[ob + 1] += v.y; sv[ob + 2] += v.z; sv[ob + 3] += v.w; }
    }
  }
  float tv[16];
  {
    float* B = lds + (buf + 1) * 4096;
#pragma unroll
    for (int g = 0; g < 16; ++g) {
      float4 v = *(const float4*)(B + (idx0 ^ (g * 4)));
      const int ob = (g & 3) * 4;
      if (g < 4) { tv[ob] = v.x; tv[ob + 1] = v.y; tv[ob + 2] = v.z; tv[ob + 3] = v.w; }
      else       { tv[ob] += v.x; tv[ob + 1] += v.y; tv[ob + 2] += v.z; tv[ob + 3] += v.w; }
    }
  }
#pragma unroll
  for (int o = 0; o < 16; ++o) {
    y[o] = (y[o] - tv[o]) * __expf(-sv[o]);
    ld -= sv[o];
  }
}

__global__ __launch_bounds__(256, 1) void k_flow(
    const float* __restrict__ nodes,
    const float* __restrict__ sW1, const float* __restrict__ sb1,
    const float* __restrict__ sW2, const float* __restrict__ sb2,
    const float* __restrict__ tW1, const float* __restrict__ tb1,
    const float* __restrict__ tW2, const float* __restrict__ tb2,
    const float* __restrict__ an_t, const float* __restrict__ loc,
    const float* __restrict__ ws, float* __restrict__ logp) {
  __shared__ float lds[16384];  // 2 dbuf x 2 mlp x 64 nodes x 64 floats
  const int lane = threadIdx.x;
  const int w = __builtin_amdgcn_readfirstlane((int)threadIdx.y);  // wave id, uniform
  const int c = blockIdx.x >> 5;
  const int node = (blockIdx.x & 31) * 64 + lane;

  const float* eas = ws;
  const float* els = ws + 16384;
  const float* CONSTc = ws + 16640;

  float ze[16], zo[16];
  {
    const float4* np = (const float4*)(nodes + node * D_);
#pragma unroll
    for (int t = 0; t < 8; ++t) {
      float4 v = np[t];
      ze[2 * t] = v.x; zo[2 * t] = v.y; ze[2 * t + 1] = v.z; zo[2 * t + 1] = v.w;
    }
  }
  // XOR bank swizzle: granule g of node n lives at n*64 + ((g ^ swz(n))*4)
  const int swzf = ((lane & 15) ^ (((lane >> 4) & 1) << 2)) * 4;
  const int idx0 = lane * 64 + swzf;
  float ld = 0.f;

  for (int k = K_ - 1; k > 0; k -= 2) {
    layer_step<1>(c, k, w, idx0, zo, ze, ld, lds, sW1, sb1, sW2, sb2, tW1, tb1,
                  tW2, tb2, an_t, eas);
    layer_step<0>(c, k - 1, w, idx0, ze, zo, ld, lds, sW1, sb1, sW2, sb2, tW1,
                  tb1, tW2, tb2, an_t, eas);
  }

  if (w == 0) {
    const float* lc = loc + c * D_;
    const float* el = els + c * D_;
    float sq = 0.f;
#pragma unroll
    for (int i = 0; i < 16; ++i) {
      float a = (ze[i] - lc[2 * i]) * el[2 * i];
      float b = (zo[i] - lc[2 * i + 1]) * el[2 * i + 1];
      sq += a * a + b * b;
    }
    logp[c * N_ + node] = ld + CONSTc[c] - 0.5f * sq;
  }
}

// Bn = exp(logp) / max(rowsum, 1e-12)  -- literal, NO max-subtraction (clamp may engage!)
__global__ __launch_bounds__(256) void k_norm(const float* __restrict__ logp,
                                              float* __restrict__ Bn) {
  __shared__ float red[256];
  const int c = blockIdx.x;
  const int t = threadIdx.x;
  float e[8];
  float part = 0.f;
#pragma unroll
  for (int r = 0; r < 8; ++r) {
    e[r] = __expf(logp[c * N_ + r * 256 + t]);
    part += e[r];
  }
  red[t] = part;
  __syncthreads();
  for (int s = 128; s > 0; s >>= 1) {
    if (t < s) red[t] += red[t + s];
    __syncthreads();
  }
  const float inv = 1.f / fmaxf(red[0], 1e-12f);
#pragma unroll
  for (int r = 0; r < 8; ++r) Bn[c * N_ + r * 256 + t] = e[r] * inv;
}

// A = S @ Bn with S = exp(S_unc)/sum(exp(S_unc))
__global__ __launch_bounds__(256) void k_A(const float* __restrict__ S_unc,
                                           const float* __restrict__ Bn,
                                           float* __restrict__ A) {
  __shared__ float sE[64];
  __shared__ float sInv;
  const int t = threadIdx.x;
  if (t < 64) sE[t] = __expf(S_unc[t]);
  __syncthreads();
  if (t == 0) {
    float tot = 0.f;
    for (int i = 0; i < 64; ++i) tot += sE[i];
    sInv = 1.f / tot;
  }
  __syncthreads();
  const int j = blockIdx.x * 256 + t;
  float b[8];
#pragma unroll
  for (int cc = 0; cc < 8; ++cc) b[cc] = Bn[cc * N_ + j];
#pragma unroll
  for (int c = 0; c < 8; ++c) {
    float acc = 0.f;
#pragma unroll
    for (int cc = 0; cc < 8; ++cc) acc += sE[c * 8 + cc] * b[cc];
    A[c * N_ + j] = acc * sInv;
  }
}

// out[i][j] = sum_c Bn[c][i] * A[c][j]; each thread does a 4x4 tile
__global__ __launch_bounds__(256) void k_out(const float* __restrict__ Bn,
                                             const float* __restrict__ A,
                                             float* __restrict__ out) {
  const int T = blockIdx.x * 256 + threadIdx.x;
  const int i0 = (T >> 9) << 2;
  const int j0 = (T & 511) << 2;
  float acc[4][4];
#pragma unroll
  for (int r = 0; r < 4; ++r)
#pragma unroll
    for (int e2 = 0; e2 < 4; ++e2) acc[r][e2] = 0.f;
#pragma unroll
  for (int cc = 0; cc < 8; ++cc) {
    const float4 bi = *(const float4*)(Bn + cc * N_ + i0);
    const float4 aj = *(const float4*)(A + cc * N_ + j0);
    const float br[4] = {bi.x, bi.y, bi.z, bi.w};
    const float ar[4] = {aj.x, aj.y, aj.z, aj.w};
#pragma unroll
    for (int r = 0; r < 4; ++r)
#pragma unroll
      for (int e2 = 0; e2 < 4; ++e2) acc[r][e2] += br[r] * ar[e2];
  }
#pragma unroll
  for (int r = 0; r < 4; ++r)
    *(float4*)(out + (i0 + r) * N_ + j0) =
        make_float4(acc[r][0], acc[r][1], acc[r][2], acc[r][3]);
}

extern "C" void kernel_launch(void* const* d_in, const int* in_sizes, int n_in,
                              void* d_out, int out_size, void* d_ws,
                              size_t ws_size, hipStream_t stream) {
  const float* nodes = (const float*)d_in[0];
  const float* sW1 = (const float*)d_in[1];
  const float* sb1 = (const float*)d_in[2];
  const float* sW2 = (const float*)d_in[3];
  const float* sb2 = (const float*)d_in[4];
  const float* tW1 = (const float*)d_in[5];
  const float* tb1 = (const float*)d_in[6];
  const float* tW2 = (const float*)d_in[7];
  const float* tb2 = (const float*)d_in[8];
  const float* an_s = (const float*)d_in[9];
  const float* an_t = (const float*)d_in[10];
  const float* loc = (const float*)d_in[11];
  const float* log_scale = (const float*)d_in[12];
  const float* S_unc = (const float*)d_in[13];
  float* out = (float*)d_out;
  float* ws = (float*)d_ws;
  float* logp = ws + 16648;
  float* Bn = ws + 33032;
  float* A = ws + 49416;

  k_pre<<<64, 256, 0, stream>>>(an_s, log_scale, ws);
  k_const<<<1, 512, 0, stream>>>(an_s, log_scale, ws);
  k_flow<<<256, dim3(64, 4), 0, stream>>>(nodes, sW1, sb1, sW2, sb2, tW1, tb1,
                                          tW2, tb2, an_t, loc, ws, logp);
  k_norm<<<8, 256, 0, stream>>>(logp, Bn);
  k_A<<<8, 256, 0, stream>>>(S_unc, Bn, A);
  k_out<<<1024, 256, 0, stream>>>(Bn, A, out);
}